// Round 1
// baseline (45.298 us; speedup 1.0000x reference)
//
#include <hip/hip_runtime.h>
#include <cstdint>
#include <cstddef>

#define PD 1024          // feature dim D (fixed by the problem)
#define PER_IMG 256      // proposals per image
#define TEMP_INV 5.0f    // 1 / TEMPERATURE (0.2)
#define IOU_THRES 0.4f

// ---------------------------------------------------------------------------
// Kernel 1: per-image masked sums of L2-normalized box rows.
// grid = B * split blocks, 256 threads (4 waves). Each block handles
// PER_IMG/split rows of image b and writes partial s_pos / s_all (D floats
// each) plus a partial positive-count to workspace. No global atomics.
// Lane l owns d-indices {(j*64+l)*4 .. +3 | j=0..3}  (coalesced float4 loads).
// ---------------------------------------------------------------------------
__global__ __launch_bounds__(256) void k1_rowsum(
    const float* __restrict__ box, const float* __restrict__ ious,
    float* __restrict__ wsPos, float* __restrict__ wsAll,
    float* __restrict__ wsCnt, int split)
{
    const int rpb  = PER_IMG / split;       // rows per block
    const int b    = blockIdx.x / split;
    const int s    = blockIdx.x % split;
    const int lane = threadIdx.x & 63;
    const int wave = threadIdx.x >> 6;      // 0..3
    const int row0 = s * rpb;

    float accP[16], accA[16];
#pragma unroll
    for (int i = 0; i < 16; ++i) { accP[i] = 0.f; accA[i] = 0.f; }
    int cnt = 0;

    for (int r = row0 + wave; r < row0 + rpb; r += 4) {
        const int grow = b * PER_IMG + r;
        const float* p = box + (size_t)grow * PD;
        float4 v[4];
#pragma unroll
        for (int j = 0; j < 4; ++j)
            v[j] = *reinterpret_cast<const float4*>(p + (j * 64 + lane) * 4);

        float ss = 0.f;
#pragma unroll
        for (int j = 0; j < 4; ++j)
            ss += v[j].x * v[j].x + v[j].y * v[j].y + v[j].z * v[j].z + v[j].w * v[j].w;
#pragma unroll
        for (int off = 32; off >= 1; off >>= 1)
            ss += __shfl_xor(ss, off, 64);

        const float inv = 1.0f / fmaxf(sqrtf(ss), 1e-12f);
        const bool pos = ious[grow] >= IOU_THRES;
        if (pos && lane == 0) ++cnt;
        const float pm = pos ? inv : 0.f;
#pragma unroll
        for (int j = 0; j < 4; ++j) {
            accA[j * 4 + 0] += v[j].x * inv;  accP[j * 4 + 0] += v[j].x * pm;
            accA[j * 4 + 1] += v[j].y * inv;  accP[j * 4 + 1] += v[j].y * pm;
            accA[j * 4 + 2] += v[j].z * inv;  accP[j * 4 + 2] += v[j].z * pm;
            accA[j * 4 + 3] += v[j].w * inv;  accP[j * 4 + 3] += v[j].w * pm;
        }
    }

    // ---- combine the 4 waves through LDS (sequential, deterministic) ----
    __shared__ float lds[2][PD];
    __shared__ int cntLds;
    if (threadIdx.x == 0) cntLds = 0;
    __syncthreads();
    if (lane == 0 && cnt) atomicAdd(&cntLds, cnt);   // LDS int atomic: associative

    for (int w = 0; w < 4; ++w) {
        if (wave == w) {
#pragma unroll
            for (int j = 0; j < 4; ++j) {
                const int d = (j * 64 + lane) * 4;
                if (w == 0) {
                    lds[0][d + 0] = accP[j * 4 + 0]; lds[1][d + 0] = accA[j * 4 + 0];
                    lds[0][d + 1] = accP[j * 4 + 1]; lds[1][d + 1] = accA[j * 4 + 1];
                    lds[0][d + 2] = accP[j * 4 + 2]; lds[1][d + 2] = accA[j * 4 + 2];
                    lds[0][d + 3] = accP[j * 4 + 3]; lds[1][d + 3] = accA[j * 4 + 3];
                } else {
                    lds[0][d + 0] += accP[j * 4 + 0]; lds[1][d + 0] += accA[j * 4 + 0];
                    lds[0][d + 1] += accP[j * 4 + 1]; lds[1][d + 1] += accA[j * 4 + 1];
                    lds[0][d + 2] += accP[j * 4 + 2]; lds[1][d + 2] += accA[j * 4 + 2];
                    lds[0][d + 3] += accP[j * 4 + 3]; lds[1][d + 3] += accA[j * 4 + 3];
                }
            }
        }
        __syncthreads();
    }

    const size_t base = (size_t)(b * split + s) * PD;
#pragma unroll
    for (int j = 0; j < 4; ++j) {
        const int d = j * 256 + threadIdx.x;
        wsPos[base + d] = lds[0][d];
        wsAll[base + d] = lds[1][d];
    }
    if (threadIdx.x == 0) wsCnt[b * split + s] = (float)cntLds;
}

// ---------------------------------------------------------------------------
// Kernel 2: per (k, b) cosine-group statistics -> softplus term.
// grid = B blocks, 256 threads. Combines split partials once per b, then
// loops over k scales.
// ---------------------------------------------------------------------------
__global__ __launch_bounds__(256) void k2_dots(
    const float* __restrict__ crop,
    const float* __restrict__ wsPos, const float* __restrict__ wsAll,
    const float* __restrict__ wsCnt, float* __restrict__ softOut,
    int split, int K, int B)
{
    const int b    = blockIdx.x;
    const int t    = threadIdx.x;
    const int lane = t & 63;
    const int wave = t >> 6;

    float cntP = 0.f;
    for (int s = 0; s < split; ++s) cntP += wsCnt[b * split + s];

    float sp[4], sa[4];
#pragma unroll
    for (int j = 0; j < 4; ++j) {
        const int d = j * 256 + t;
        float p = 0.f, a = 0.f;
        for (int s = 0; s < split; ++s) {
            const size_t off = (size_t)(b * split + s) * PD + d;
            p += wsPos[off];
            a += wsAll[off];
        }
        sp[j] = p; sa[j] = a;
    }

    __shared__ float red[3][4];
    for (int k = 0; k < K; ++k) {
        float ssz = 0.f, dpP = 0.f, dpA = 0.f;
#pragma unroll
        for (int j = 0; j < 4; ++j) {
            const int d = j * 256 + t;
            const float z = crop[((size_t)k * B + b) * PD + d];
            ssz += z * z;
            dpP += sp[j] * z;
            dpA += sa[j] * z;
        }
#pragma unroll
        for (int off = 32; off >= 1; off >>= 1) {
            ssz += __shfl_xor(ssz, off, 64);
            dpP += __shfl_xor(dpP, off, 64);
            dpA += __shfl_xor(dpA, off, 64);
        }
        if (lane == 0) { red[0][wave] = ssz; red[1][wave] = dpP; red[2][wave] = dpA; }
        __syncthreads();
        if (t == 0) {
            float S = 0.f, P = 0.f, A = 0.f;
            for (int w = 0; w < 4; ++w) { S += red[0][w]; P += red[1][w]; A += red[2][w]; }
            const float invz = 1.0f / fmaxf(sqrtf(S), 1e-12f);
            const float simP = -(P * invz) / cntP;
            const float simN = -((A - P) * invz) / ((float)PER_IMG - cntP);
            const float x = (simN - simP) * TEMP_INV;
            // stable softplus: max(x,0) + log1p(exp(-|x|))
            softOut[k * B + b] = fmaxf(x, 0.f) + log1pf(expf(-fabsf(x)));
        }
        __syncthreads();
    }
}

// ---------------------------------------------------------------------------
// Kernel 3: L[k] = sum_b softplus; out = min_k L / B.  One block of B threads.
// ---------------------------------------------------------------------------
__global__ void k3_final(const float* __restrict__ softOut,
                         float* __restrict__ out, int K, int B)
{
    const int t    = threadIdx.x;
    const int lane = t & 63;
    const int wave = t >> 6;
    const int nw   = blockDim.x >> 6;
    __shared__ float red[16];
    float m = 3.402823466e38f;   // only thread 0 uses

    for (int k = 0; k < K; ++k) {
        float v = (t < B) ? softOut[k * B + t] : 0.f;
#pragma unroll
        for (int off = 32; off >= 1; off >>= 1)
            v += __shfl_xor(v, off, 64);
        if (lane == 0) red[wave] = v;
        __syncthreads();
        if (t == 0) {
            float s = 0.f;
            for (int w = 0; w < nw; ++w) s += red[w];
            m = fminf(m, s);
        }
        __syncthreads();
    }
    if (t == 0) out[0] = m / (float)B;
}

// ---------------------------------------------------------------------------
extern "C" void kernel_launch(void* const* d_in, const int* in_sizes, int n_in,
                              void* d_out, int out_size, void* d_ws, size_t ws_size,
                              hipStream_t stream)
{
    const float* box  = (const float*)d_in[0];   // [N, D] f32
    const float* crop = (const float*)d_in[1];   // [K, B, D] f32
    const float* ious = (const float*)d_in[3];   // [N] f32

    const int N = in_sizes[3];
    const int B = N / PER_IMG;                   // 128
    const int D = in_sizes[0] / N;               // 1024 (layout assumes PD)
    const int K = in_sizes[1] / (B * D);         // 4

    // pick the largest split whose partial buffers fit in the workspace
    int split = 8;
    auto need = [&](int s) -> size_t {
        return (size_t)B * s * PD * 2 * sizeof(float)   // wsPos + wsAll
             + (size_t)B * s * sizeof(float)            // wsCnt
             + (size_t)K * B * sizeof(float) + 1024;    // softOut + slack
    };
    while (split > 1 && need(split) > ws_size) split >>= 1;

    char* w = (char*)d_ws;
    float* wsPos = (float*)w;  w += (size_t)B * split * PD * sizeof(float);
    float* wsAll = (float*)w;  w += (size_t)B * split * PD * sizeof(float);
    float* wsCnt = (float*)w;  w += (size_t)B * split * sizeof(float);
    float* softO = (float*)w;

    hipLaunchKernelGGL(k1_rowsum, dim3(B * split), dim3(256), 0, stream,
                       box, ious, wsPos, wsAll, wsCnt, split);
    hipLaunchKernelGGL(k2_dots, dim3(B), dim3(256), 0, stream,
                       crop, wsPos, wsAll, wsCnt, softO, split, K, B);
    hipLaunchKernelGGL(k3_final, dim3(1), dim3(128), 0, stream,
                       softO, (float*)d_out, K, B);
}

// Round 2
// 43.451 us; speedup vs baseline: 1.0425x; 1.0425x over previous
//
#include <hip/hip_runtime.h>
#include <cstdint>
#include <cstddef>

#define PD 1024          // feature dim D (fixed by the problem)
#define PER_IMG 256      // proposals per image
#define TEMP_INV 5.0f    // 1 / TEMPERATURE (0.2)
#define IOU_THRES 0.4f

typedef float f32x4 __attribute__((ext_vector_type(4)));

__device__ inline f32x4 ntload4(const float* p) {
    return __builtin_nontemporal_load(reinterpret_cast<const f32x4*>(p));
}

// ---------------------------------------------------------------------------
// Kernel 1: per-image masked sums of L2-normalized box rows.
// grid = B * split blocks, 256 threads (4 waves). Each wave handles
// RPB/4 contiguous rows, processed 4 at a time: 16 nontemporal float4 loads
// in flight, 4 interleaved shuffle-reduce chains (hides both HBM latency and
// shuffle latency). Lane l owns d-indices {(j*64+l)*4 .. +3 | j=0..3}.
// ---------------------------------------------------------------------------
template<int RPB>   // rows per block = PER_IMG / split
__global__ __launch_bounds__(256) void k1_rowsum(
    const float* __restrict__ box, const float* __restrict__ ious,
    float* __restrict__ wsPos, float* __restrict__ wsAll,
    float* __restrict__ wsCnt, int split)
{
    constexpr int RW = RPB / 4;             // rows per wave
    const int b    = blockIdx.x / split;
    const int s    = blockIdx.x % split;
    const int lane = threadIdx.x & 63;
    const int wave = threadIdx.x >> 6;      // 0..3
    const int row0 = s * RPB + wave * RW;   // wave's first row (contiguous run)

    float accP[16], accA[16];
#pragma unroll
    for (int i = 0; i < 16; ++i) { accP[i] = 0.f; accA[i] = 0.f; }
    int cnt = 0;

    const size_t growBase = (size_t)b * PER_IMG + row0;
    const float* rp = box + growBase * PD;

#pragma unroll 1
    for (int it = 0; it < RW; it += 4) {
        // ---- issue 16 independent vector loads (4 rows x 4 segments) ----
        f32x4 v[4][4];
#pragma unroll
        for (int r = 0; r < 4; ++r)
#pragma unroll
            for (int j = 0; j < 4; ++j)
                v[r][j] = ntload4(rp + (size_t)(it + r) * PD + (j * 64 + lane) * 4);

        float iou[4];
#pragma unroll
        for (int r = 0; r < 4; ++r) iou[r] = ious[growBase + it + r];

        // ---- 4 independent squared-norm partials ----
        float ss[4];
#pragma unroll
        for (int r = 0; r < 4; ++r) {
            float t = 0.f;
#pragma unroll
            for (int j = 0; j < 4; ++j)
                t += v[r][j][0] * v[r][j][0] + v[r][j][1] * v[r][j][1]
                   + v[r][j][2] * v[r][j][2] + v[r][j][3] * v[r][j][3];
            ss[r] = t;
        }
        // ---- interleaved butterfly reduce: 4 chains, throughput-bound ----
#pragma unroll
        for (int off = 32; off >= 1; off >>= 1) {
#pragma unroll
            for (int r = 0; r < 4; ++r)
                ss[r] += __shfl_xor(ss[r], off, 64);
        }

#pragma unroll
        for (int r = 0; r < 4; ++r) {
            const float inv = 1.0f / fmaxf(sqrtf(ss[r]), 1e-12f);
            const bool pos = iou[r] >= IOU_THRES;
            if (pos && lane == 0) ++cnt;
            const float pm = pos ? inv : 0.f;
#pragma unroll
            for (int j = 0; j < 4; ++j) {
                accA[j * 4 + 0] += v[r][j][0] * inv;  accP[j * 4 + 0] += v[r][j][0] * pm;
                accA[j * 4 + 1] += v[r][j][1] * inv;  accP[j * 4 + 1] += v[r][j][1] * pm;
                accA[j * 4 + 2] += v[r][j][2] * inv;  accP[j * 4 + 2] += v[r][j][2] * pm;
                accA[j * 4 + 3] += v[r][j][3] * inv;  accP[j * 4 + 3] += v[r][j][3] * pm;
            }
        }
    }

    // ---- combine the 4 waves through LDS (sequential, deterministic) ----
    __shared__ float lds[2][PD];
    __shared__ int cntLds;
    if (threadIdx.x == 0) cntLds = 0;
    __syncthreads();
    if (lane == 0 && cnt) atomicAdd(&cntLds, cnt);   // LDS int atomic: associative

    for (int w = 0; w < 4; ++w) {
        if (wave == w) {
#pragma unroll
            for (int j = 0; j < 4; ++j) {
                const int d = (j * 64 + lane) * 4;
                if (w == 0) {
#pragma unroll
                    for (int c = 0; c < 4; ++c) {
                        lds[0][d + c] = accP[j * 4 + c];
                        lds[1][d + c] = accA[j * 4 + c];
                    }
                } else {
#pragma unroll
                    for (int c = 0; c < 4; ++c) {
                        lds[0][d + c] += accP[j * 4 + c];
                        lds[1][d + c] += accA[j * 4 + c];
                    }
                }
            }
        }
        __syncthreads();
    }

    const size_t base = (size_t)(b * split + s) * PD;
#pragma unroll
    for (int j = 0; j < 4; ++j) {
        const int d = j * 256 + threadIdx.x;
        wsPos[base + d] = lds[0][d];
        wsAll[base + d] = lds[1][d];
    }
    if (threadIdx.x == 0) wsCnt[b * split + s] = (float)cntLds;
}

// ---------------------------------------------------------------------------
// Kernel 2: per (k, b) cosine-group statistics -> softplus term.
// grid = B blocks, 256 threads. float4 loads matching k1's write layout.
// ---------------------------------------------------------------------------
__global__ __launch_bounds__(256) void k2_dots(
    const float* __restrict__ crop,
    const float* __restrict__ wsPos, const float* __restrict__ wsAll,
    const float* __restrict__ wsCnt, float* __restrict__ softOut,
    int split, int K, int B)
{
    const int b    = blockIdx.x;
    const int t    = threadIdx.x;
    const int lane = t & 63;
    const int wave = t >> 6;

    float cntP = 0.f;
    for (int s = 0; s < split; ++s) cntP += wsCnt[b * split + s];

    f32x4 sp[4], sa[4];
#pragma unroll
    for (int j = 0; j < 4; ++j) { sp[j] = 0.f; sa[j] = 0.f; }
    for (int s = 0; s < split; ++s) {
        const float* basePos = wsPos + (size_t)(b * split + s) * PD;
        const float* baseAll = wsAll + (size_t)(b * split + s) * PD;
#pragma unroll
        for (int j = 0; j < 4; ++j) {
            const int d = (j * 64 + lane) * 4;
            sp[j] += *reinterpret_cast<const f32x4*>(basePos + d);
            sa[j] += *reinterpret_cast<const f32x4*>(baseAll + d);
        }
    }

    __shared__ float red[3][4];
    for (int k = 0; k < K; ++k) {
        const float* zp = crop + ((size_t)k * B + b) * PD;
        float ssz = 0.f, dpP = 0.f, dpA = 0.f;
#pragma unroll
        for (int j = 0; j < 4; ++j) {
            const int d = (j * 64 + lane) * 4;
            const f32x4 z = *reinterpret_cast<const f32x4*>(zp + d);
#pragma unroll
            for (int c = 0; c < 4; ++c) {
                ssz += z[c] * z[c];
                dpP += sp[j][c] * z[c];
                dpA += sa[j][c] * z[c];
            }
        }
#pragma unroll
        for (int off = 32; off >= 1; off >>= 1) {
            ssz += __shfl_xor(ssz, off, 64);
            dpP += __shfl_xor(dpP, off, 64);
            dpA += __shfl_xor(dpA, off, 64);
        }
        if (lane == 0) { red[0][wave] = ssz; red[1][wave] = dpP; red[2][wave] = dpA; }
        __syncthreads();
        if (t == 0) {
            float S = 0.f, P = 0.f, A = 0.f;
            for (int w = 0; w < 4; ++w) { S += red[0][w]; P += red[1][w]; A += red[2][w]; }
            const float invz = 1.0f / fmaxf(sqrtf(S), 1e-12f);
            const float simP = -(P * invz) / cntP;
            const float simN = -((A - P) * invz) / ((float)PER_IMG - cntP);
            const float x = (simN - simP) * TEMP_INV;
            // stable softplus: max(x,0) + log1p(exp(-|x|))
            softOut[k * B + b] = fmaxf(x, 0.f) + log1pf(expf(-fabsf(x)));
        }
        __syncthreads();
    }
}

// ---------------------------------------------------------------------------
// Kernel 3: L[k] = sum_b softplus; out = min_k L / B.  One block of B threads.
// ---------------------------------------------------------------------------
__global__ void k3_final(const float* __restrict__ softOut,
                         float* __restrict__ out, int K, int B)
{
    const int t    = threadIdx.x;
    const int lane = t & 63;
    const int wave = t >> 6;
    const int nw   = blockDim.x >> 6;
    __shared__ float red[16];
    float m = 3.402823466e38f;   // only thread 0 uses

    for (int k = 0; k < K; ++k) {
        float v = (t < B) ? softOut[k * B + t] : 0.f;
#pragma unroll
        for (int off = 32; off >= 1; off >>= 1)
            v += __shfl_xor(v, off, 64);
        if (lane == 0) red[wave] = v;
        __syncthreads();
        if (t == 0) {
            float s = 0.f;
            for (int w = 0; w < nw; ++w) s += red[w];
            m = fminf(m, s);
        }
        __syncthreads();
    }
    if (t == 0) out[0] = m / (float)B;
}

// ---------------------------------------------------------------------------
extern "C" void kernel_launch(void* const* d_in, const int* in_sizes, int n_in,
                              void* d_out, int out_size, void* d_ws, size_t ws_size,
                              hipStream_t stream)
{
    const float* box  = (const float*)d_in[0];   // [N, D] f32
    const float* crop = (const float*)d_in[1];   // [K, B, D] f32
    const float* ious = (const float*)d_in[3];   // [N] f32

    const int N = in_sizes[3];
    const int B = N / PER_IMG;                   // 128
    const int D = in_sizes[0] / N;               // 1024 (layout assumes PD)
    const int K = in_sizes[1] / (B * D);         // 4

    // pick the largest split whose partial buffers fit in the workspace
    int split = 8;
    auto need = [&](int s) -> size_t {
        return (size_t)B * s * PD * 2 * sizeof(float)   // wsPos + wsAll
             + (size_t)B * s * sizeof(float)            // wsCnt
             + (size_t)K * B * sizeof(float) + 1024;    // softOut + slack
    };
    while (split > 1 && need(split) > ws_size) split >>= 1;

    char* w = (char*)d_ws;
    float* wsPos = (float*)w;  w += (size_t)B * split * PD * sizeof(float);
    float* wsAll = (float*)w;  w += (size_t)B * split * PD * sizeof(float);
    float* wsCnt = (float*)w;  w += (size_t)B * split * sizeof(float);
    float* softO = (float*)w;

    switch (split) {
    case 8:
        hipLaunchKernelGGL((k1_rowsum<32>), dim3(B * 8), dim3(256), 0, stream,
                           box, ious, wsPos, wsAll, wsCnt, 8);
        break;
    case 4:
        hipLaunchKernelGGL((k1_rowsum<64>), dim3(B * 4), dim3(256), 0, stream,
                           box, ious, wsPos, wsAll, wsCnt, 4);
        break;
    case 2:
        hipLaunchKernelGGL((k1_rowsum<128>), dim3(B * 2), dim3(256), 0, stream,
                           box, ious, wsPos, wsAll, wsCnt, 2);
        break;
    default:
        hipLaunchKernelGGL((k1_rowsum<256>), dim3(B), dim3(256), 0, stream,
                           box, ious, wsPos, wsAll, wsCnt, 1);
        break;
    }
    hipLaunchKernelGGL(k2_dots, dim3(B), dim3(256), 0, stream,
                       crop, wsPos, wsAll, wsCnt, softO, split, K, B);
    hipLaunchKernelGGL(k3_final, dim3(1), dim3(128), 0, stream,
                       softO, (float*)d_out, K, B);
}

// Round 3
// 31.442 us; speedup vs baseline: 1.4407x; 1.3820x over previous
//
#include <hip/hip_runtime.h>
#include <cstdint>
#include <cstddef>

#define PD 1024          // feature dim D (fixed by the problem)
#define PER_IMG 256      // proposals per image
#define TEMP_INV 5.0f    // 1 / TEMPERATURE (0.2)
#define IOU_THRES 0.4f
#define SPLIT 8          // blocks per image in k1
#define RPB (PER_IMG / SPLIT)   // rows per block  = 32
#define RW  (RPB / 4)           // rows per wave   = 8

typedef float f32x4 __attribute__((ext_vector_type(4)));

__device__ inline f32x4 ntload4(const float* p) {
    return __builtin_nontemporal_load(reinterpret_cast<const f32x4*>(p));
}

// ---------------------------------------------------------------------------
// Kernel 1: per-image masked sums of L2-normalized box rows, reduced
// IMMEDIATELY against the (L2-resident) crop vectors to 9 scalars per block.
//   block (b,s): rows [s*RPB, (s+1)*RPB) of image b
//   outputs: pdotP[k] = dot(sum_pos_rows row_n, z_raw[k,b])   (k = 0..K-1)
//            pdotA[k] = dot(sum_all_rows row_n, z_raw[k,b])
//            cnt      = # positive rows in this block
//            (s==0 only) ssz[k] = dot(z_raw, z_raw)
// The z normalization factor is applied later (linear).
// ---------------------------------------------------------------------------
__global__ __launch_bounds__(256) void k1_rowsum(
    const float* __restrict__ box, const float* __restrict__ ious,
    const float* __restrict__ crop,
    float* __restrict__ wsP, float* __restrict__ wsA,
    float* __restrict__ wsZ, float* __restrict__ wsCnt, int B, int K)
{
    const int b    = blockIdx.x / SPLIT;
    const int s    = blockIdx.x % SPLIT;
    const int lane = threadIdx.x & 63;
    const int wv   = threadIdx.x >> 6;      // 0..3
    const int row0 = s * RPB + wv * RW;     // wave's first row (contiguous)

    float accP[16], accA[16];
#pragma unroll
    for (int i = 0; i < 16; ++i) { accP[i] = 0.f; accA[i] = 0.f; }
    int cnt = 0;

    const size_t growBase = (size_t)b * PER_IMG + row0;
    const float* rp = box + growBase * PD;

#pragma unroll 1
    for (int it = 0; it < RW; it += 4) {
        // ---- 16 independent nontemporal vector loads (4 rows x 4 segs) ----
        f32x4 v[4][4];
#pragma unroll
        for (int r = 0; r < 4; ++r)
#pragma unroll
            for (int j = 0; j < 4; ++j)
                v[r][j] = ntload4(rp + (size_t)(it + r) * PD + (j * 64 + lane) * 4);

        float iou[4];
#pragma unroll
        for (int r = 0; r < 4; ++r) iou[r] = ious[growBase + it + r];

        float ss[4];
#pragma unroll
        for (int r = 0; r < 4; ++r) {
            float t = 0.f;
#pragma unroll
            for (int j = 0; j < 4; ++j)
                t += v[r][j][0] * v[r][j][0] + v[r][j][1] * v[r][j][1]
                   + v[r][j][2] * v[r][j][2] + v[r][j][3] * v[r][j][3];
            ss[r] = t;
        }
#pragma unroll
        for (int off = 32; off >= 1; off >>= 1) {
#pragma unroll
            for (int r = 0; r < 4; ++r)
                ss[r] += __shfl_xor(ss[r], off, 64);
        }

#pragma unroll
        for (int r = 0; r < 4; ++r) {
            const float inv = 1.0f / fmaxf(sqrtf(ss[r]), 1e-12f);
            const bool pos = iou[r] >= IOU_THRES;
            if (pos && lane == 0) ++cnt;
            const float pm = pos ? inv : 0.f;
#pragma unroll
            for (int j = 0; j < 4; ++j) {
#pragma unroll
                for (int c = 0; c < 4; ++c) {
                    accA[j * 4 + c] += v[r][j][c] * inv;
                    accP[j * 4 + c] += v[r][j][c] * pm;
                }
            }
        }
    }

    // ---- each wave writes its partial sums to its own LDS quadrant ----
    __shared__ float ldsP[4][PD];
    __shared__ float ldsA[4][PD];
    __shared__ int cntLds;
    if (threadIdx.x == 0) cntLds = 0;
#pragma unroll
    for (int j = 0; j < 4; ++j) {
        const int d = (j * 64 + lane) * 4;
        f32x4 p = { accP[j*4+0], accP[j*4+1], accP[j*4+2], accP[j*4+3] };
        f32x4 a = { accA[j*4+0], accA[j*4+1], accA[j*4+2], accA[j*4+3] };
        *reinterpret_cast<f32x4*>(&ldsP[wv][d]) = p;
        *reinterpret_cast<f32x4*>(&ldsA[wv][d]) = a;
    }
    __syncthreads();
    if (lane == 0 && cnt) atomicAdd(&cntLds, cnt);

    // ---- wave k: combine quadrants inline, dot against z[k,b] (L2-hot) ----
    if (wv < K) {
        const float* zp = crop + ((size_t)wv * B + b) * PD;
        float dotP = 0.f, dotA = 0.f, ssz = 0.f;
#pragma unroll
        for (int j = 0; j < 4; ++j) {
            const int d = (j * 64 + lane) * 4;
            const f32x4 z  = *reinterpret_cast<const f32x4*>(zp + d);
            f32x4 sP = *reinterpret_cast<const f32x4*>(&ldsP[0][d]);
            f32x4 sA = *reinterpret_cast<const f32x4*>(&ldsA[0][d]);
#pragma unroll
            for (int w = 1; w < 4; ++w) {
                sP += *reinterpret_cast<const f32x4*>(&ldsP[w][d]);
                sA += *reinterpret_cast<const f32x4*>(&ldsA[w][d]);
            }
#pragma unroll
            for (int c = 0; c < 4; ++c) {
                dotP += sP[c] * z[c];
                dotA += sA[c] * z[c];
                ssz  += z[c]  * z[c];
            }
        }
#pragma unroll
        for (int off = 32; off >= 1; off >>= 1) {
            dotP += __shfl_xor(dotP, off, 64);
            dotA += __shfl_xor(dotA, off, 64);
            ssz  += __shfl_xor(ssz,  off, 64);
        }
        if (lane == 0) {
            const size_t kb = (size_t)wv * B + b;
            wsP[kb * SPLIT + s] = dotP;
            wsA[kb * SPLIT + s] = dotA;
            if (s == 0) wsZ[kb] = ssz;
        }
    }
    __syncthreads();
    if (threadIdx.x == 0) wsCnt[b * SPLIT + s] = (float)cntLds;
}

// ---------------------------------------------------------------------------
// Kernel 2: combine split partials -> softplus per (k,b) -> sum_b -> min_k.
// One block, 256 threads; total input ~40 KB.
// ---------------------------------------------------------------------------
__global__ __launch_bounds__(256) void k2_final(
    const float* __restrict__ wsP, const float* __restrict__ wsA,
    const float* __restrict__ wsZ, const float* __restrict__ wsCnt,
    float* __restrict__ out, int B, int K)
{
    const int t    = threadIdx.x;
    const int lane = t & 63;
    const int wv   = t >> 6;

    __shared__ float spl[512];      // K*B <= 512 for this problem
    __shared__ float red[4];

    for (int pair = t; pair < K * B; pair += 256) {
        const int b = pair % B;
        float P = 0.f, A = 0.f, C = 0.f;
#pragma unroll
        for (int s = 0; s < SPLIT; ++s) {
            P += wsP[(size_t)pair * SPLIT + s];
            A += wsA[(size_t)pair * SPLIT + s];
            C += wsCnt[b * SPLIT + s];
        }
        const float invz = 1.0f / fmaxf(sqrtf(wsZ[pair]), 1e-12f);
        const float simP = -(P * invz) / C;
        const float simN = -((A - P) * invz) / ((float)PER_IMG - C);
        const float x = (simN - simP) * TEMP_INV;
        spl[pair] = fmaxf(x, 0.f) + log1pf(expf(-fabsf(x)));  // softplus
    }
    __syncthreads();

    if (wv < K) {
        float v = 0.f;
        for (int b = lane; b < B; b += 64) v += spl[wv * B + b];
#pragma unroll
        for (int off = 32; off >= 1; off >>= 1)
            v += __shfl_xor(v, off, 64);
        if (lane == 0) red[wv] = v;
    }
    __syncthreads();
    if (t == 0) {
        float m = red[0];
        for (int k = 1; k < K; ++k) m = fminf(m, red[k]);
        out[0] = m / (float)B;
    }
}

// ---------------------------------------------------------------------------
extern "C" void kernel_launch(void* const* d_in, const int* in_sizes, int n_in,
                              void* d_out, int out_size, void* d_ws, size_t ws_size,
                              hipStream_t stream)
{
    const float* box  = (const float*)d_in[0];   // [N, D] f32
    const float* crop = (const float*)d_in[1];   // [K, B, D] f32
    const float* ious = (const float*)d_in[3];   // [N] f32

    const int N = in_sizes[3];
    const int B = N / PER_IMG;                   // 128
    const int D = in_sizes[0] / N;               // 1024 (layout fixed = PD)
    const int K = in_sizes[1] / (B * D);         // 4 (assumed <= 4)

    char* w = (char*)d_ws;
    float* wsP   = (float*)w;  w += (size_t)K * B * SPLIT * sizeof(float);
    float* wsA   = (float*)w;  w += (size_t)K * B * SPLIT * sizeof(float);
    float* wsZ   = (float*)w;  w += (size_t)K * B * sizeof(float);
    float* wsCnt = (float*)w;

    hipLaunchKernelGGL(k1_rowsum, dim3(B * SPLIT), dim3(256), 0, stream,
                       box, ious, crop, wsP, wsA, wsZ, wsCnt, B, K);
    hipLaunchKernelGGL(k2_final, dim3(1), dim3(256), 0, stream,
                       wsP, wsA, wsZ, wsCnt, (float*)d_out, B, K);
}